// Round 13
// baseline (370.316 us; speedup 1.0000x reference)
//
#include <hip/hip_runtime.h>

typedef unsigned short u16;
typedef unsigned int u32;
typedef short bf16x8 __attribute__((ext_vector_type(8)));
typedef float f32x16 __attribute__((ext_vector_type(16)));
typedef u16 u16x8 __attribute__((ext_vector_type(8)));

#define DIM 96
#define PLANE (DIM*DIM)   // 9216
#define S 884736          // 96^3
#define C 64
#define HALF 32
#define PARTS 16
#define EPS 1e-5f
#define DSPLIT 4
#define DCHUNK (DIM/DSPLIT)  // 24, even (2-round unroll keeps LDS buf ids static)

// f32 LDS tile: rows of 108 floats; data cols 0..95 at +8; zeros at [0..7],[104..107]
#define RPADF 108
#define LROWS 18
#define LBUFF (LROWS*RPADF)   // 1944 floats per buffer

#define MFMA32(a,b,c) __builtin_amdgcn_mfma_f32_32x32x16_bf16(a,b,c,0,0,0)

__device__ __forceinline__ u16 f2bf(float f) {          // RNE, finite inputs
  u32 u = __builtin_bit_cast(u32, f);
  return (u16)((u + 0x7FFFu + ((u >> 16) & 1u)) >> 16);
}
__device__ __forceinline__ float bf2f(u16 h) {
  return __builtin_bit_cast(float, (u32)h << 16);
}
__device__ __forceinline__ u32 cvt_pk_bf16(float lo, float hi) {  // lo->[15:0], hi->[31:16]
  u32 r;
  asm("v_cvt_pk_bf16_f32 %0, %1, %2" : "=v"(r) : "v"(lo), "v"(hi));
  return r;
}
__device__ __forceinline__ float silu(float v) { return v / (1.f + __expf(-v)); }
__device__ __forceinline__ u16x8 zero8() {
  u16x8 z;
  #pragma unroll
  for (int i = 0; i < 8; ++i) z[i] = 0;
  return z;
}

// ---- K1: per-channel partial sums (deterministic) + bf16 copy of x -----------
__global__ __launch_bounds__(256) void k1_stats(const float* __restrict__ x,
                                                u16* __restrict__ xb,
                                                float* __restrict__ psum,
                                                float* __restrict__ psq) {
  const int bid = blockIdx.x;              // 0 .. C*PARTS-1
  const int ch = bid / PARTS, part = bid % PARTS;
  const int chunk = S / PARTS;
  const size_t base = (size_t)ch * S + (size_t)part * chunk;
  const float4* p = (const float4*)(x + base);
  ushort4* xb4 = (ushort4*)(xb + base);
  const int n4 = chunk / 4;
  float s = 0.f, q = 0.f;
  for (int i = threadIdx.x; i < n4; i += 256) {
    float4 v = p[i];
    s += (v.x + v.y) + (v.z + v.w);
    q += (v.x * v.x + v.y * v.y) + (v.z * v.z + v.w * v.w);
    union { u32 u[2]; ushort4 v4; } o;
    o.u[0] = cvt_pk_bf16(v.x, v.y);
    o.u[1] = cvt_pk_bf16(v.z, v.w);
    xb4[i] = o.v4;
  }
  #pragma unroll
  for (int off = 32; off > 0; off >>= 1) {
    s += __shfl_down(s, off);
    q += __shfl_down(q, off);
  }
  __shared__ float ls[4], lq[4];
  const int wid = threadIdx.x >> 6, lane = threadIdx.x & 63;
  if (lane == 0) { ls[wid] = s; lq[wid] = q; }
  __syncthreads();
  if (threadIdx.x == 0) {
    psum[bid] = (ls[0] + ls[1]) + (ls[2] + ls[3]);
    psq[bid]  = (lq[0] + lq[1]) + (lq[2] + lq[3]);
  }
}

// ------ K1b: finalize stats; emit bf16 folded in_proj W, bf16 out_proj W ------
__global__ __launch_bounds__(64) void k1b_prep(const float* __restrict__ psum,
    const float* __restrict__ psq,
    const float* __restrict__ norm_w, const float* __restrict__ norm_b,
    const float* __restrict__ in_w, const float* __restrict__ in_b,
    const float* __restrict__ out_w,
    u16* __restrict__ Wp, float* __restrict__ biasp, u16* __restrict__ Wo) {
  __shared__ float a_s[C], b2_s[C];
  const int t = threadIdx.x;               // 0..63 (output row o)
  float s = 0.f, q = 0.f;
  for (int i = 0; i < PARTS; ++i) { s += psum[t * PARTS + i]; q += psq[t * PARTS + i]; }
  const float inv = 1.f / (float)S;
  const float mu = s * inv;
  const float var = q * inv - mu * mu;
  const float rsig = rsqrtf(var + EPS);
  const float a = norm_w[t] * rsig;
  const float b2 = norm_b[t] - mu * a;
  a_s[t] = a; b2_s[t] = b2;
  __syncthreads();
  float bp = in_b[t];
  for (int c = 0; c < C; ++c) {
    const float w = in_w[t * C + c];
    Wp[t * C + c] = f2bf(w * a_s[c]);      // folded norm scale, row-major [o][c]
    bp += b2_s[c] * w;                     // folded norm shift
    Wo[t * C + c] = f2bf(out_w[t * C + c]);
  }
  biasp[t] = bp;
}

// ------ K2: 1x1 in_proj, 32x32x16 MFMA, even/odd interleaved voxel tiles ------
__global__ __launch_bounds__(256) void k2_mfma(const u16* __restrict__ xb,
    const u16* __restrict__ Wp, const float* __restrict__ biasp,
    u16* __restrict__ xp) {
  const int lane = threadIdx.x & 63, wid = threadIdx.x >> 6;
  const int n = lane & 31, hf = lane >> 5;
  const int v0 = blockIdx.x * 256 + wid * 64;      // 64 voxels per wave
  bf16x8 A[2][4];                                  // [o-tile][k-slice]
  #pragma unroll
  for (int t = 0; t < 2; ++t)
    #pragma unroll
    for (int s = 0; s < 4; ++s)
      A[t][s] = *(const bf16x8*)(Wp + (t * 32 + n) * C + s * 16 + hf * 8);

  f32x16 accE[2], accO[2];
  #pragma unroll
  for (int t = 0; t < 2; ++t)
    #pragma unroll
    for (int r = 0; r < 16; ++r) {
      const float b = biasp[t * 32 + (r & 3) + 8 * (r >> 2) + 4 * hf];
      accE[t][r] = b; accO[t][r] = b;
    }

  #pragma unroll
  for (int s = 0; s < 4; ++s) {
    union { u16 u[8]; bf16x8 v; } BE, BO;
    #pragma unroll
    for (int j = 0; j < 8; ++j) {
      const u32 xv = *(const u32*)(xb + (size_t)(s * 16 + hf * 8 + j) * S + v0 + 2 * n);
      BE.u[j] = (u16)(xv & 0xFFFFu); BO.u[j] = (u16)(xv >> 16);
    }
    #pragma unroll
    for (int t = 0; t < 2; ++t) {
      accE[t] = MFMA32(A[t][s], BE.v, accE[t]);
      accO[t] = MFMA32(A[t][s], BO.v, accO[t]);
    }
  }
  #pragma unroll
  for (int t = 0; t < 2; ++t)
    #pragma unroll
    for (int r = 0; r < 16; ++r) {
      const int o = t * 32 + (r & 3) + 8 * (r >> 2) + 4 * hf;
      *(u32*)(xp + (size_t)o * S + v0 + 2 * n) = cvt_pk_bf16(accE[t][r], accO[t][r]);
    }
}

// ---- depthwise 3x3x3: f32 LDS planes, A/B tap-carry, dbuf, 1 barrier/step ----
__device__ __forceinline__ void fma3(float* __restrict__ a,
    const float* __restrict__ r, float t0, float t1, float t2) {
  #pragma unroll
  for (int i = 0; i < 8; ++i) a[i] = fmaf(t0, r[i], a[i]);
  #pragma unroll
  for (int i = 0; i < 8; ++i) a[i] = fmaf(t1, r[i + 1], a[i]);
  #pragma unroll
  for (int i = 0; i < 8; ++i) a[i] = fmaf(t2, r[i + 2], a[i]);
}

// convA: c<32: t1[c] = SiLU(conv_ssm(xp[c])); c>=32: z_hi[c-32] = SiLU(conv_sym(xp[c]))
// convB: z_lo[c] = conv_mamba(t1[c])
template<bool SILU>
__global__ __launch_bounds__(192) void dwconv(const u16* __restrict__ srcA,
    const float* __restrict__ kwA, const float* __restrict__ bA,
    u16* __restrict__ dstA,
    const float* __restrict__ kwB, const float* __restrict__ bB,
    u16* __restrict__ dstB) {
  __shared__ float lds[2][LBUFF];
  const int c = blockIdx.z;
  const u16* src = srcA + (size_t)c * S;
  u16* dst; const float* kwp; float bias;
  if (c < HALF) { dst = dstA + (size_t)c * S;          kwp = kwA + c * 27;          bias = bA[c]; }
  else          { dst = dstB + (size_t)(c - HALF) * S; kwp = kwB + (c - HALF) * 27; bias = bB[c - HALF]; }
  float kw[27];                            // wave-uniform
  #pragma unroll
  for (int i = 0; i < 27; ++i) kw[i] = kwp[i];

  const int tx = threadIdx.x, ty = threadIdx.y;    // 12 x 16
  const int tid = ty * 12 + tx;
  const int w8 = tx * 8;
  const int h0 = blockIdx.x * 16;
  const int d0 = blockIdx.y * DCHUNK;

  // zero pads once: per row, floats [0..7] and [104..107]; both buffers.
  if (tid < 36) {
    const int b = tid / 18, r = tid % 18;
    float4 z4 = make_float4(0.f, 0.f, 0.f, 0.f);
    *(float4*)&lds[b][r * RPADF + 0] = z4;
    *(float4*)&lds[b][r * RPADF + 4] = z4;
    *(float4*)&lds[b][r * RPADF + 104] = z4;
  }

  // staging assignment: chunk c0 = tid, chunk c1 = 192+tid (tid<24). 216 = 18x12.
  const int s_row0 = tid / 12, s_cc0 = tid % 12;
  const int s_row1 = (192 + tid) / 12, s_cc1 = (192 + tid) % 12;
  const bool has2 = tid < 24;
  const int s_h0 = h0 - 1 + s_row0;
  const int s_h1 = h0 - 1 + s_row1;
  const bool h0ok = (unsigned)s_h0 < DIM;
  const bool h1ok = has2 && ((unsigned)s_h1 < DIM);
  u16x8 vs0, vs1;

  #define STAGE_LOAD(DD) { \
    vs0 = zero8(); vs1 = zero8(); \
    if (((unsigned)(DD) < DIM) && h0ok) \
      vs0 = *(const u16x8*)(src + (size_t)(DD) * PLANE + s_h0 * DIM + s_cc0 * 8); \
    if (((unsigned)(DD) < DIM) && h1ok) \
      vs1 = *(const u16x8*)(src + (size_t)(DD) * PLANE + s_h1 * DIM + s_cc1 * 8); }

  #define STAGE_WRITE(WB) { \
    float4 f0, f1; \
    f0.x = bf2f(vs0[0]); f0.y = bf2f(vs0[1]); f0.z = bf2f(vs0[2]); f0.w = bf2f(vs0[3]); \
    f1.x = bf2f(vs0[4]); f1.y = bf2f(vs0[5]); f1.z = bf2f(vs0[6]); f1.w = bf2f(vs0[7]); \
    *(float4*)&lds[WB][8 + s_row0 * RPADF + s_cc0 * 8] = f0; \
    *(float4*)&lds[WB][8 + s_row0 * RPADF + s_cc0 * 8 + 4] = f1; \
    if (has2) { \
      f0.x = bf2f(vs1[0]); f0.y = bf2f(vs1[1]); f0.z = bf2f(vs1[2]); f0.w = bf2f(vs1[3]); \
      f1.x = bf2f(vs1[4]); f1.y = bf2f(vs1[5]); f1.z = bf2f(vs1[6]); f1.w = bf2f(vs1[7]); \
      *(float4*)&lds[WB][8 + s_row1 * RPADF + s_cc1 * 8] = f0; \
      *(float4*)&lds[WB][8 + s_row1 * RPADF + s_cc1 * 8 + 4] = f1; } }

  float r0[10], r1[10], r2[10];
  float A[8], B[8], o8[8];

  // LDS window read: 2x b128 + 2x b32, no converts; pads supply zeros.
  #define LOADROW(R, ROWI, RB) { \
    const float* _lb = &lds[RB][8 + (ROWI) * RPADF + w8]; \
    const float4 _a = *(const float4*)_lb; \
    const float4 _b = *(const float4*)(_lb + 4); \
    R[0] = _lb[-1]; \
    R[1] = _a.x; R[2] = _a.y; R[3] = _a.z; R[4] = _a.w; \
    R[5] = _b.x; R[6] = _b.y; R[7] = _b.z; R[8] = _b.w; \
    R[9] = _lb[8]; }

  #define LOADROWS(RB) { LOADROW(r0, ty, RB); LOADROW(r1, ty + 1, RB); LOADROW(r2, ty + 2, RB); }

  #define CBLK(ACC, K0) { \
    fma3(ACC, r0, kw[(K0) + 0], kw[(K0) + 1], kw[(K0) + 2]); \
    fma3(ACC, r1, kw[(K0) + 3], kw[(K0) + 4], kw[(K0) + 5]); \
    fma3(ACC, r2, kw[(K0) + 6], kw[(K0) + 7], kw[(K0) + 8]); }

  // ---- prologue ----
  STAGE_LOAD(d0 - 1);            // d0==0 -> zeros (bounds check)
  STAGE_WRITE(0);
  __syncthreads();

  LOADROWS(0);                   // plane d0-1
  STAGE_LOAD(d0);
  #pragma unroll
  for (int i = 0; i < 8; ++i) B[i] = bias;
  CBLK(B, 0);
  STAGE_WRITE(1);
  __syncthreads();

  LOADROWS(1);                   // plane d0
  STAGE_LOAD(d0 + 1);
  #pragma unroll
  for (int i = 0; i < 8; ++i) { A[i] = B[i]; B[i] = bias; }
  CBLK(A, 9);
  CBLK(B, 0);
  STAGE_WRITE(0);
  __syncthreads();

  // ---- main: round(d): stage-load d+2 first (latency), read buf, compute ----
  u16* db = dst + (size_t)d0 * PLANE + (size_t)(h0 + ty) * DIM + w8;

  #define ROUND_BODY(D, RB, WB, DO_STG) { \
    if (DO_STG) STAGE_LOAD((D) + 2); \
    LOADROWS(RB); \
    _Pragma("unroll") \
    for (int i = 0; i < 8; ++i) o8[i] = A[i]; \
    CBLK(o8, 18); \
    _Pragma("unroll") \
    for (int i = 0; i < 8; ++i) A[i] = B[i]; \
    CBLK(A, 9); \
    _Pragma("unroll") \
    for (int i = 0; i < 8; ++i) B[i] = bias; \
    CBLK(B, 0); \
    if (SILU) { \
      _Pragma("unroll") \
      for (int i = 0; i < 8; ++i) o8[i] = silu(o8[i]); \
    } \
    union { u32 u[4]; u16x8 v; } _o; \
    _Pragma("unroll") \
    for (int i = 0; i < 4; ++i) _o.u[i] = cvt_pk_bf16(o8[2 * i], o8[2 * i + 1]); \
    *(u16x8*)db = _o.v; \
    db += PLANE; \
    if (DO_STG) STAGE_WRITE(WB); \
    __syncthreads(); }

  #pragma unroll 1
  for (int d = d0; d < d0 + DCHUNK; d += 2) {
    ROUND_BODY(d, 0, 1, true);                                   // output d
    ROUND_BODY(d + 1, 1, 0, (d + 2) < d0 + DCHUNK);              // output d+1
  }
  #undef ROUND_BODY
  #undef CBLK
  #undef LOADROWS
  #undef LOADROW
  #undef STAGE_WRITE
  #undef STAGE_LOAD
}

// --- K4b: 1x1 out_proj (32x32x16 MFMA) + bias + bf16 residual -> fp32 out -----
__global__ __launch_bounds__(256) void k4b_mfma(const u16* __restrict__ z_lo,
    const u16* __restrict__ z_hi, const u16* __restrict__ xb,
    const u16* __restrict__ Wo, const float* __restrict__ ob,
    float* __restrict__ out) {
  const int lane = threadIdx.x & 63, wid = threadIdx.x >> 6;
  const int n = lane & 31, hf = lane >> 5;
  const int v0 = blockIdx.x * 256 + wid * 64;
  bf16x8 A[2][4];
  #pragma unroll
  for (int t = 0; t < 2; ++t)
    #pragma unroll
    for (int s = 0; s < 4; ++s)
      A[t][s] = *(const bf16x8*)(Wo + (t * 32 + n) * C + s * 16 + hf * 8);

  f32x16 accE[2], accO[2];
  #pragma unroll
  for (int t = 0; t < 2; ++t)
    #pragma unroll
    for (int r = 0; r < 16; ++r) {
      const float b = ob[t * 32 + (r & 3) + 8 * (r >> 2) + 4 * hf];
      accE[t][r] = b; accO[t][r] = b;
    }

  #pragma unroll
  for (int s = 0; s < 4; ++s) {
    const u16* zbase = (s < 2) ? z_lo + (size_t)(s * 16) * S
                               : z_hi + (size_t)((s - 2) * 16) * S;
    union { u16 u[8]; bf16x8 v; } BE, BO;
    #pragma unroll
    for (int j = 0; j < 8; ++j) {
      const u32 zv = *(const u32*)(zbase + (size_t)(hf * 8 + j) * S + v0 + 2 * n);
      BE.u[j] = (u16)(zv & 0xFFFFu); BO.u[j] = (u16)(zv >> 16);
    }
    #pragma unroll
    for (int t = 0; t < 2; ++t) {
      accE[t] = MFMA32(A[t][s], BE.v, accE[t]);
      accO[t] = MFMA32(A[t][s], BO.v, accO[t]);
    }
  }
  #pragma unroll
  for (int t = 0; t < 2; ++t)
    #pragma unroll
    for (int r = 0; r < 16; ++r) {
      const int o = t * 32 + (r & 3) + 8 * (r >> 2) + 4 * hf;
      const u32 xr = *(const u32*)(xb + (size_t)o * S + v0 + 2 * n);
      float2 ov;
      ov.x = accE[t][r] + bf2f((u16)(xr & 0xFFFFu));
      ov.y = accO[t][r] + bf2f((u16)(xr >> 16));
      *(float2*)(out + (size_t)o * S + v0 + 2 * n) = ov;
    }
}

extern "C" void kernel_launch(void* const* d_in, const int* in_sizes, int n_in,
                              void* d_out, int out_size, void* d_ws, size_t ws_size,
                              hipStream_t stream) {
  const float* x      = (const float*)d_in[0];
  const float* norm_w = (const float*)d_in[1];
  const float* norm_b = (const float*)d_in[2];
  const float* in_w   = (const float*)d_in[3];
  const float* in_b   = (const float*)d_in[4];
  const float* ssm_w  = (const float*)d_in[5];
  const float* ssm_b  = (const float*)d_in[6];
  const float* mam_w  = (const float*)d_in[7];
  const float* mam_b  = (const float*)d_in[8];
  const float* sym_w  = (const float*)d_in[9];
  const float* sym_b  = (const float*)d_in[10];
  const float* out_w  = (const float*)d_in[11];
  const float* out_b  = (const float*)d_in[12];
  float* out = (float*)d_out;

  // Workspace (u16 units). z_lo ALIASES xp[0:32] (dead after convA; convB is
  // launched after convA completes, stream-ordered). Total ~340 MB.
  u16* xb   = (u16*)d_ws;                      // C*S bf16 copy of x (113.2 MB)
  u16* xp   = xb + (size_t)C * S;              // C*S bf16 (113.2 MB)
  u16* t1   = xp + (size_t)C * S;              // HALF*S bf16 (56.6 MB)
  u16* z_hi = t1 + (size_t)HALF * S;           // HALF*S bf16 (56.6 MB)
  u16* z_lo = xp;                              // alias, HALF*S
  float* psum  = (float*)(z_hi + (size_t)HALF * S);  // C*PARTS
  float* psq   = psum + C * PARTS;             // C*PARTS
  u16* Wp      = (u16*)(psq + C * PARTS);      // C*C bf16
  u16* Wo      = Wp + C * C;                   // C*C bf16
  float* biasp = (float*)(Wo + C * C);         // C fp32

  k1_stats<<<C * PARTS, 256, 0, stream>>>(x, xb, psum, psq);
  k1b_prep<<<1, 64, 0, stream>>>(psum, psq, norm_w, norm_b, in_w, in_b, out_w,
                                 Wp, biasp, Wo);
  k2_mfma<<<S / 256, 256, 0, stream>>>(xb, Wp, biasp, xp);
  // convA: ssm on xp[0:32] -> t1 ; sym on xp[32:64] -> z_hi (both SiLU)
  dwconv<true><<<dim3(DIM / 16, DSPLIT, C), dim3(12, 16, 1), 0, stream>>>(
      xp, ssm_w, ssm_b, t1, sym_w, sym_b, z_hi);
  // convB: mamba on t1 -> z_lo (no activation)
  dwconv<false><<<dim3(DIM / 16, DSPLIT, HALF), dim3(12, 16, 1), 0, stream>>>(
      t1, mam_w, mam_b, z_lo, mam_w, mam_b, z_lo);
  k4b_mfma<<<S / 256, 256, 0, stream>>>(z_lo, z_hi, xb, Wo, out_b, out);
}

// Round 14
// 362.935 us; speedup vs baseline: 1.0203x; 1.0203x over previous
//
#include <hip/hip_runtime.h>

typedef unsigned short u16;
typedef unsigned int u32;
typedef short bf16x8 __attribute__((ext_vector_type(8)));
typedef float f32x16 __attribute__((ext_vector_type(16)));
typedef u16 u16x8 __attribute__((ext_vector_type(8)));

#define DIM 96
#define PLANE (DIM*DIM)   // 9216
#define S 884736          // 96^3
#define C 64
#define HALF 32
#define PARTS 16
#define EPS 1e-5f
#define DSPLIT 4
#define DCHUNK (DIM/DSPLIT)  // 24, divisible by 4 (pair ids static in unroll)

// f32 LDS plane: rows of 108 floats; data cols 0..95 at +8; zeros at [0..7],[104..107]
#define RPADF 108
#define LROWS 18
#define LBUFF (LROWS*RPADF)   // 1944 floats per plane buffer

#define MFMA32(a,b,c) __builtin_amdgcn_mfma_f32_32x32x16_bf16(a,b,c,0,0,0)

__device__ __forceinline__ u16 f2bf(float f) {          // RNE, finite inputs
  u32 u = __builtin_bit_cast(u32, f);
  return (u16)((u + 0x7FFFu + ((u >> 16) & 1u)) >> 16);
}
__device__ __forceinline__ float bf2f(u16 h) {
  return __builtin_bit_cast(float, (u32)h << 16);
}
__device__ __forceinline__ u32 cvt_pk_bf16(float lo, float hi) {  // lo->[15:0], hi->[31:16]
  u32 r;
  asm("v_cvt_pk_bf16_f32 %0, %1, %2" : "=v"(r) : "v"(lo), "v"(hi));
  return r;
}
__device__ __forceinline__ float silu(float v) { return v / (1.f + __expf(-v)); }
__device__ __forceinline__ u16x8 zero8() {
  u16x8 z;
  #pragma unroll
  for (int i = 0; i < 8; ++i) z[i] = 0;
  return z;
}

// ---- K1: per-channel partial sums (deterministic) + bf16 copy of x -----------
__global__ __launch_bounds__(256) void k1_stats(const float* __restrict__ x,
                                                u16* __restrict__ xb,
                                                float* __restrict__ psum,
                                                float* __restrict__ psq) {
  const int bid = blockIdx.x;              // 0 .. C*PARTS-1
  const int ch = bid / PARTS, part = bid % PARTS;
  const int chunk = S / PARTS;
  const size_t base = (size_t)ch * S + (size_t)part * chunk;
  const float4* p = (const float4*)(x + base);
  ushort4* xb4 = (ushort4*)(xb + base);
  const int n4 = chunk / 4;
  float s = 0.f, q = 0.f;
  for (int i = threadIdx.x; i < n4; i += 256) {
    float4 v = p[i];
    s += (v.x + v.y) + (v.z + v.w);
    q += (v.x * v.x + v.y * v.y) + (v.z * v.z + v.w * v.w);
    union { u32 u[2]; ushort4 v4; } o;
    o.u[0] = cvt_pk_bf16(v.x, v.y);
    o.u[1] = cvt_pk_bf16(v.z, v.w);
    xb4[i] = o.v4;
  }
  #pragma unroll
  for (int off = 32; off > 0; off >>= 1) {
    s += __shfl_down(s, off);
    q += __shfl_down(q, off);
  }
  __shared__ float ls[4], lq[4];
  const int wid = threadIdx.x >> 6, lane = threadIdx.x & 63;
  if (lane == 0) { ls[wid] = s; lq[wid] = q; }
  __syncthreads();
  if (threadIdx.x == 0) {
    psum[bid] = (ls[0] + ls[1]) + (ls[2] + ls[3]);
    psq[bid]  = (lq[0] + lq[1]) + (lq[2] + lq[3]);
  }
}

// ------ K1b: finalize stats; emit bf16 folded in_proj W, bf16 out_proj W ------
__global__ __launch_bounds__(64) void k1b_prep(const float* __restrict__ psum,
    const float* __restrict__ psq,
    const float* __restrict__ norm_w, const float* __restrict__ norm_b,
    const float* __restrict__ in_w, const float* __restrict__ in_b,
    const float* __restrict__ out_w,
    u16* __restrict__ Wp, float* __restrict__ biasp, u16* __restrict__ Wo) {
  __shared__ float a_s[C], b2_s[C];
  const int t = threadIdx.x;               // 0..63 (output row o)
  float s = 0.f, q = 0.f;
  for (int i = 0; i < PARTS; ++i) { s += psum[t * PARTS + i]; q += psq[t * PARTS + i]; }
  const float inv = 1.f / (float)S;
  const float mu = s * inv;
  const float var = q * inv - mu * mu;
  const float rsig = rsqrtf(var + EPS);
  const float a = norm_w[t] * rsig;
  const float b2 = norm_b[t] - mu * a;
  a_s[t] = a; b2_s[t] = b2;
  __syncthreads();
  float bp = in_b[t];
  for (int c = 0; c < C; ++c) {
    const float w = in_w[t * C + c];
    Wp[t * C + c] = f2bf(w * a_s[c]);      // folded norm scale, row-major [o][c]
    bp += b2_s[c] * w;                     // folded norm shift
    Wo[t * C + c] = f2bf(out_w[t * C + c]);
  }
  biasp[t] = bp;
}

// ------ K2: 1x1 in_proj, 32x32x16 MFMA, even/odd interleaved voxel tiles ------
__global__ __launch_bounds__(256) void k2_mfma(const u16* __restrict__ xb,
    const u16* __restrict__ Wp, const float* __restrict__ biasp,
    u16* __restrict__ xp) {
  const int lane = threadIdx.x & 63, wid = threadIdx.x >> 6;
  const int n = lane & 31, hf = lane >> 5;
  const int v0 = blockIdx.x * 256 + wid * 64;      // 64 voxels per wave
  bf16x8 A[2][4];                                  // [o-tile][k-slice]
  #pragma unroll
  for (int t = 0; t < 2; ++t)
    #pragma unroll
    for (int s = 0; s < 4; ++s)
      A[t][s] = *(const bf16x8*)(Wp + (t * 32 + n) * C + s * 16 + hf * 8);

  f32x16 accE[2], accO[2];
  #pragma unroll
  for (int t = 0; t < 2; ++t)
    #pragma unroll
    for (int r = 0; r < 16; ++r) {
      const float b = biasp[t * 32 + (r & 3) + 8 * (r >> 2) + 4 * hf];
      accE[t][r] = b; accO[t][r] = b;
    }

  #pragma unroll
  for (int s = 0; s < 4; ++s) {
    union { u16 u[8]; bf16x8 v; } BE, BO;
    #pragma unroll
    for (int j = 0; j < 8; ++j) {
      const u32 xv = *(const u32*)(xb + (size_t)(s * 16 + hf * 8 + j) * S + v0 + 2 * n);
      BE.u[j] = (u16)(xv & 0xFFFFu); BO.u[j] = (u16)(xv >> 16);
    }
    #pragma unroll
    for (int t = 0; t < 2; ++t) {
      accE[t] = MFMA32(A[t][s], BE.v, accE[t]);
      accO[t] = MFMA32(A[t][s], BO.v, accO[t]);
    }
  }
  #pragma unroll
  for (int t = 0; t < 2; ++t)
    #pragma unroll
    for (int r = 0; r < 16; ++r) {
      const int o = t * 32 + (r & 3) + 8 * (r >> 2) + 4 * hf;
      *(u32*)(xp + (size_t)o * S + v0 + 2 * n) = cvt_pk_bf16(accE[t][r], accO[t][r]);
    }
}

// -- depthwise 3x3x3: paired f32 LDS planes, A/B tap-carry, 2-plane rounds -----
__device__ __forceinline__ void fma3(float* __restrict__ a,
    const float* __restrict__ r, float t0, float t1, float t2) {
  #pragma unroll
  for (int i = 0; i < 8; ++i) a[i] = fmaf(t0, r[i], a[i]);
  #pragma unroll
  for (int i = 0; i < 8; ++i) a[i] = fmaf(t1, r[i + 1], a[i]);
  #pragma unroll
  for (int i = 0; i < 8; ++i) a[i] = fmaf(t2, r[i + 2], a[i]);
}

// convA: c<32: t1[c] = SiLU(conv_ssm(xp[c])); c>=32: z_hi[c-32] = SiLU(conv_sym(xp[c]))
// convB: z_lo[c] = conv_mamba(t1[c])
template<bool SILU>
__global__ __launch_bounds__(192) void dwconv(const u16* __restrict__ srcA,
    const float* __restrict__ kwA, const float* __restrict__ bA,
    u16* __restrict__ dstA,
    const float* __restrict__ kwB, const float* __restrict__ bB,
    u16* __restrict__ dstB) {
  __shared__ float lds[2][2][LBUFF];       // [pair][slot][plane tile]
  const int c = blockIdx.z;
  const u16* src = srcA + (size_t)c * S;
  u16* dst; const float* kwp; float bias;
  if (c < HALF) { dst = dstA + (size_t)c * S;          kwp = kwA + c * 27;          bias = bA[c]; }
  else          { dst = dstB + (size_t)(c - HALF) * S; kwp = kwB + (c - HALF) * 27; bias = bB[c - HALF]; }
  float kw[27];                            // wave-uniform
  #pragma unroll
  for (int i = 0; i < 27; ++i) kw[i] = kwp[i];

  const int tx = threadIdx.x, ty = threadIdx.y;    // 12 x 16
  const int tid = ty * 12 + tx;
  const int w8 = tx * 8;
  const int h0 = blockIdx.x * 16;
  const int d0 = blockIdx.y * DCHUNK;

  // zero pad chunks once: 2 pairs x 2 slots x 18 rows = 72 rows; never rewritten
  if (tid < 72) {
    float* rowp = &lds[tid / 36][(tid / 18) & 1][(tid % 18) * RPADF];
    const float4 z4 = make_float4(0.f, 0.f, 0.f, 0.f);
    *(float4*)&rowp[0] = z4;
    *(float4*)&rowp[4] = z4;
    *(float4*)&rowp[104] = z4;
  }

  // staging: chunk c0 = tid, chunk c1 = 192+tid (tid<24); 216 chunks = 18 rows x 12
  const int s_row0 = tid / 12, s_cc0 = tid % 12;
  const int s_row1 = (192 + tid) / 12, s_cc1 = (192 + tid) % 12;
  const bool has2 = tid < 24;
  const int s_h0 = h0 - 1 + s_row0;
  const int s_h1 = h0 - 1 + s_row1;
  const bool h0ok = (unsigned)s_h0 < DIM;
  const bool h1ok = has2 && ((unsigned)s_h1 < DIM);
  u16x8 vA0, vA1, vB0, vB1;                // raw bf16 for planes D1 (A) and D2 (B)

  #define LD8(DD, HH, CC) (*(const u16x8*)(src + (size_t)(DD) * PLANE + (HH) * DIM + (CC) * 8))

  #define STAGE_LOAD2(D1, D2) { \
    vA0 = zero8(); vA1 = zero8(); vB0 = zero8(); vB1 = zero8(); \
    if (((unsigned)(D1) < DIM) && h0ok) vA0 = LD8(D1, s_h0, s_cc0); \
    if (((unsigned)(D1) < DIM) && h1ok) vA1 = LD8(D1, s_h1, s_cc1); \
    if (((unsigned)(D2) < DIM) && h0ok) vB0 = LD8(D2, s_h0, s_cc0); \
    if (((unsigned)(D2) < DIM) && h1ok) vB1 = LD8(D2, s_h1, s_cc1); }

  #define WR8(P, SL, ROW, CC, V) { \
    float4 f0, f1; \
    f0.x = bf2f(V[0]); f0.y = bf2f(V[1]); f0.z = bf2f(V[2]); f0.w = bf2f(V[3]); \
    f1.x = bf2f(V[4]); f1.y = bf2f(V[5]); f1.z = bf2f(V[6]); f1.w = bf2f(V[7]); \
    *(float4*)&lds[P][SL][8 + (ROW) * RPADF + (CC) * 8] = f0; \
    *(float4*)&lds[P][SL][8 + (ROW) * RPADF + (CC) * 8 + 4] = f1; }

  #define STAGE_WRITE2(P) { \
    WR8(P, 0, s_row0, s_cc0, vA0); \
    WR8(P, 1, s_row0, s_cc0, vB0); \
    if (has2) { WR8(P, 0, s_row1, s_cc1, vA1); WR8(P, 1, s_row1, s_cc1, vB1); } }

  float r0[10], r1[10], r2[10];
  float A[8], B[8], o8[8];

  #define LOADROW(R, ROWI, P, SL) { \
    const float* _lb = &lds[P][SL][8 + (ROWI) * RPADF + w8]; \
    const float4 _a = *(const float4*)_lb; \
    const float4 _b = *(const float4*)(_lb + 4); \
    R[0] = _lb[-1]; \
    R[1] = _a.x; R[2] = _a.y; R[3] = _a.z; R[4] = _a.w; \
    R[5] = _b.x; R[6] = _b.y; R[7] = _b.z; R[8] = _b.w; \
    R[9] = _lb[8]; }

  #define LOADROWS(P, SL) { LOADROW(r0, ty, P, SL); LOADROW(r1, ty + 1, P, SL); LOADROW(r2, ty + 2, P, SL); }

  #define CBLK(ACC, K0) { \
    fma3(ACC, r0, kw[(K0) + 0], kw[(K0) + 1], kw[(K0) + 2]); \
    fma3(ACC, r1, kw[(K0) + 3], kw[(K0) + 4], kw[(K0) + 5]); \
    fma3(ACC, r2, kw[(K0) + 6], kw[(K0) + 7], kw[(K0) + 8]); }

  u16* db = dst + (size_t)d0 * PLANE + (size_t)(h0 + ty) * DIM + w8;

  // consume one plane from (P,SL): out = A + C2; A = B + C1; B = bias + C0; store
  #define CSTEP(P, SL) { \
    LOADROWS(P, SL); \
    _Pragma("unroll") \
    for (int i = 0; i < 8; ++i) o8[i] = A[i]; \
    CBLK(o8, 18); \
    _Pragma("unroll") \
    for (int i = 0; i < 8; ++i) A[i] = B[i]; \
    CBLK(A, 9); \
    _Pragma("unroll") \
    for (int i = 0; i < 8; ++i) B[i] = bias; \
    CBLK(B, 0); \
    if (SILU) { \
      _Pragma("unroll") \
      for (int i = 0; i < 8; ++i) o8[i] = silu(o8[i]); \
    } \
    union { u32 u[4]; u16x8 v; } _o; \
    _Pragma("unroll") \
    for (int i = 0; i < 4; ++i) _o.u[i] = cvt_pk_bf16(o8[2 * i], o8[2 * i + 1]); \
    *(u16x8*)db = _o.v; \
    db += PLANE; }

  // ---- prologue: planes d0-1, d0 through pair1; prime pair0 with d0+1, d0+2 --
  STAGE_LOAD2(d0 - 1, d0);
  STAGE_WRITE2(1);
  __syncthreads();

  LOADROWS(1, 0);                          // plane d0-1
  #pragma unroll
  for (int i = 0; i < 8; ++i) B[i] = bias;
  CBLK(B, 0);
  LOADROWS(1, 1);                          // plane d0
  #pragma unroll
  for (int i = 0; i < 8; ++i) { A[i] = B[i]; B[i] = bias; }
  CBLK(A, 9);
  CBLK(B, 0);
  STAGE_LOAD2(d0 + 1, d0 + 2);
  STAGE_WRITE2(0);
  __syncthreads();

  // ---- main: round(r): issue loads r+3,r+4; outputs r, r+1; write pair P^1 ---
  #define ROUND(R, P, DO_STG) { \
    if (DO_STG) STAGE_LOAD2((R) + 3, (R) + 4); \
    CSTEP(P, 0); \
    CSTEP(P, 1); \
    if (DO_STG) STAGE_WRITE2(P ^ 1); \
    __syncthreads(); }

  #pragma unroll 1
  for (int it = 0; it < DCHUNK / 4; ++it) {   // pair ids static per body
    const int r = d0 + 4 * it;
    ROUND(r, 0, true);
    ROUND(r + 2, 1, (4 * it + 4) < DCHUNK);
  }
  #undef ROUND
  #undef CSTEP
  #undef CBLK
  #undef LOADROWS
  #undef LOADROW
  #undef STAGE_WRITE2
  #undef WR8
  #undef STAGE_LOAD2
  #undef LD8
}

// --- K4b: 1x1 out_proj (32x32x16 MFMA) + bias + bf16 residual -> fp32 out -----
__global__ __launch_bounds__(256) void k4b_mfma(const u16* __restrict__ z_lo,
    const u16* __restrict__ z_hi, const u16* __restrict__ xb,
    const u16* __restrict__ Wo, const float* __restrict__ ob,
    float* __restrict__ out) {
  const int lane = threadIdx.x & 63, wid = threadIdx.x >> 6;
  const int n = lane & 31, hf = lane >> 5;
  const int v0 = blockIdx.x * 256 + wid * 64;
  bf16x8 A[2][4];
  #pragma unroll
  for (int t = 0; t < 2; ++t)
    #pragma unroll
    for (int s = 0; s < 4; ++s)
      A[t][s] = *(const bf16x8*)(Wo + (t * 32 + n) * C + s * 16 + hf * 8);

  f32x16 accE[2], accO[2];
  #pragma unroll
  for (int t = 0; t < 2; ++t)
    #pragma unroll
    for (int r = 0; r < 16; ++r) {
      const float b = ob[t * 32 + (r & 3) + 8 * (r >> 2) + 4 * hf];
      accE[t][r] = b; accO[t][r] = b;
    }

  #pragma unroll
  for (int s = 0; s < 4; ++s) {
    const u16* zbase = (s < 2) ? z_lo + (size_t)(s * 16) * S
                               : z_hi + (size_t)((s - 2) * 16) * S;
    union { u16 u[8]; bf16x8 v; } BE, BO;
    #pragma unroll
    for (int j = 0; j < 8; ++j) {
      const u32 zv = *(const u32*)(zbase + (size_t)(hf * 8 + j) * S + v0 + 2 * n);
      BE.u[j] = (u16)(zv & 0xFFFFu); BO.u[j] = (u16)(zv >> 16);
    }
    #pragma unroll
    for (int t = 0; t < 2; ++t) {
      accE[t] = MFMA32(A[t][s], BE.v, accE[t]);
      accO[t] = MFMA32(A[t][s], BO.v, accO[t]);
    }
  }
  #pragma unroll
  for (int t = 0; t < 2; ++t)
    #pragma unroll
    for (int r = 0; r < 16; ++r) {
      const int o = t * 32 + (r & 3) + 8 * (r >> 2) + 4 * hf;
      const u32 xr = *(const u32*)(xb + (size_t)o * S + v0 + 2 * n);
      float2 ov;
      ov.x = accE[t][r] + bf2f((u16)(xr & 0xFFFFu));
      ov.y = accO[t][r] + bf2f((u16)(xr >> 16));
      *(float2*)(out + (size_t)o * S + v0 + 2 * n) = ov;
    }
}

extern "C" void kernel_launch(void* const* d_in, const int* in_sizes, int n_in,
                              void* d_out, int out_size, void* d_ws, size_t ws_size,
                              hipStream_t stream) {
  const float* x      = (const float*)d_in[0];
  const float* norm_w = (const float*)d_in[1];
  const float* norm_b = (const float*)d_in[2];
  const float* in_w   = (const float*)d_in[3];
  const float* in_b   = (const float*)d_in[4];
  const float* ssm_w  = (const float*)d_in[5];
  const float* ssm_b  = (const float*)d_in[6];
  const float* mam_w  = (const float*)d_in[7];
  const float* mam_b  = (const float*)d_in[8];
  const float* sym_w  = (const float*)d_in[9];
  const float* sym_b  = (const float*)d_in[10];
  const float* out_w  = (const float*)d_in[11];
  const float* out_b  = (const float*)d_in[12];
  float* out = (float*)d_out;

  // Workspace (u16 units). z_lo ALIASES xp[0:32] (dead after convA; convB is
  // launched after convA completes, stream-ordered). Total ~340 MB.
  u16* xb   = (u16*)d_ws;                      // C*S bf16 copy of x (113.2 MB)
  u16* xp   = xb + (size_t)C * S;              // C*S bf16 (113.2 MB)
  u16* t1   = xp + (size_t)C * S;              // HALF*S bf16 (56.6 MB)
  u16* z_hi = t1 + (size_t)HALF * S;           // HALF*S bf16 (56.6 MB)
  u16* z_lo = xp;                              // alias, HALF*S
  float* psum  = (float*)(z_hi + (size_t)HALF * S);  // C*PARTS
  float* psq   = psum + C * PARTS;             // C*PARTS
  u16* Wp      = (u16*)(psq + C * PARTS);      // C*C bf16
  u16* Wo      = Wp + C * C;                   // C*C bf16
  float* biasp = (float*)(Wo + C * C);         // C fp32

  k1_stats<<<C * PARTS, 256, 0, stream>>>(x, xb, psum, psq);
  k1b_prep<<<1, 64, 0, stream>>>(psum, psq, norm_w, norm_b, in_w, in_b, out_w,
                                 Wp, biasp, Wo);
  k2_mfma<<<S / 256, 256, 0, stream>>>(xb, Wp, biasp, xp);
  // convA: ssm on xp[0:32] -> t1 ; sym on xp[32:64] -> z_hi (both SiLU)
  dwconv<true><<<dim3(DIM / 16, DSPLIT, C), dim3(12, 16, 1), 0, stream>>>(
      xp, ssm_w, ssm_b, t1, sym_w, sym_b, z_hi);
  // convB: mamba on t1 -> z_lo (no activation)
  dwconv<false><<<dim3(DIM / 16, DSPLIT, HALF), dim3(12, 16, 1), 0, stream>>>(
      t1, mam_w, mam_b, z_lo, mam_w, mam_b, z_lo);
  k4b_mfma<<<S / 256, 256, 0, stream>>>(z_lo, z_hi, xb, Wo, out_b, out);
}

// Round 15
// 353.388 us; speedup vs baseline: 1.0479x; 1.0270x over previous
//
#include <hip/hip_runtime.h>

typedef unsigned short u16;
typedef unsigned int u32;
typedef short bf16x8 __attribute__((ext_vector_type(8)));
typedef float f32x16 __attribute__((ext_vector_type(16)));
typedef u16 u16x8 __attribute__((ext_vector_type(8)));

#define DIM 96
#define PLANE (DIM*DIM)   // 9216
#define S 884736          // 96^3
#define C 64
#define HALF 32
#define PARTS 16
#define EPS 1e-5f

// bf16 LDS tile: rows of 104 u16 (data cols 0..95 at +8, zero pads at 104*k..104*k+7)
#define RPAD 104
#define LROWS 18
#define LBUF (8 + LROWS*RPAD)   // 1880 u16 per buffer

#define MFMA32(a,b,c) __builtin_amdgcn_mfma_f32_32x32x16_bf16(a,b,c,0,0,0)

__device__ __forceinline__ u16 f2bf(float f) {          // RNE, finite inputs
  u32 u = __builtin_bit_cast(u32, f);
  return (u16)((u + 0x7FFFu + ((u >> 16) & 1u)) >> 16);
}
__device__ __forceinline__ float bf2f(u16 h) {
  return __builtin_bit_cast(float, (u32)h << 16);
}
__device__ __forceinline__ u32 cvt_pk_bf16(float lo, float hi) {  // lo->[15:0], hi->[31:16]
  u32 r;
  asm("v_cvt_pk_bf16_f32 %0, %1, %2" : "=v"(r) : "v"(lo), "v"(hi));
  return r;
}
__device__ __forceinline__ float silu(float v) { return v / (1.f + __expf(-v)); }
__device__ __forceinline__ u16x8 zero8() {
  u16x8 z;
  #pragma unroll
  for (int i = 0; i < 8; ++i) z[i] = 0;
  return z;
}

// ---- K1: per-channel partial sums (deterministic) + bf16 copy of x -----------
__global__ __launch_bounds__(256) void k1_stats(const float* __restrict__ x,
                                                u16* __restrict__ xb,
                                                float* __restrict__ psum,
                                                float* __restrict__ psq) {
  const int bid = blockIdx.x;              // 0 .. C*PARTS-1
  const int ch = bid / PARTS, part = bid % PARTS;
  const int chunk = S / PARTS;
  const size_t base = (size_t)ch * S + (size_t)part * chunk;
  const float4* p = (const float4*)(x + base);
  ushort4* xb4 = (ushort4*)(xb + base);
  const int n4 = chunk / 4;
  float s = 0.f, q = 0.f;
  for (int i = threadIdx.x; i < n4; i += 256) {
    float4 v = p[i];
    s += (v.x + v.y) + (v.z + v.w);
    q += (v.x * v.x + v.y * v.y) + (v.z * v.z + v.w * v.w);
    union { u32 u[2]; ushort4 v4; } o;
    o.u[0] = cvt_pk_bf16(v.x, v.y);
    o.u[1] = cvt_pk_bf16(v.z, v.w);
    xb4[i] = o.v4;
  }
  #pragma unroll
  for (int off = 32; off > 0; off >>= 1) {
    s += __shfl_down(s, off);
    q += __shfl_down(q, off);
  }
  __shared__ float ls[4], lq[4];
  const int wid = threadIdx.x >> 6, lane = threadIdx.x & 63;
  if (lane == 0) { ls[wid] = s; lq[wid] = q; }
  __syncthreads();
  if (threadIdx.x == 0) {
    psum[bid] = (ls[0] + ls[1]) + (ls[2] + ls[3]);
    psq[bid]  = (lq[0] + lq[1]) + (lq[2] + lq[3]);
  }
}

// ------ K1b: finalize stats; emit bf16 folded in_proj W, bf16 out_proj W ------
__global__ __launch_bounds__(64) void k1b_prep(const float* __restrict__ psum,
    const float* __restrict__ psq,
    const float* __restrict__ norm_w, const float* __restrict__ norm_b,
    const float* __restrict__ in_w, const float* __restrict__ in_b,
    const float* __restrict__ out_w,
    u16* __restrict__ Wp, float* __restrict__ biasp, u16* __restrict__ Wo) {
  __shared__ float a_s[C], b2_s[C];
  const int t = threadIdx.x;               // 0..63 (output row o)
  float s = 0.f, q = 0.f;
  for (int i = 0; i < PARTS; ++i) { s += psum[t * PARTS + i]; q += psq[t * PARTS + i]; }
  const float inv = 1.f / (float)S;
  const float mu = s * inv;
  const float var = q * inv - mu * mu;
  const float rsig = rsqrtf(var + EPS);
  const float a = norm_w[t] * rsig;
  const float b2 = norm_b[t] - mu * a;
  a_s[t] = a; b2_s[t] = b2;
  __syncthreads();
  float bp = in_b[t];
  for (int c = 0; c < C; ++c) {
    const float w = in_w[t * C + c];
    Wp[t * C + c] = f2bf(w * a_s[c]);      // folded norm scale, row-major [o][c]
    bp += b2_s[c] * w;                     // folded norm shift
    Wo[t * C + c] = f2bf(out_w[t * C + c]);
  }
  biasp[t] = bp;
}

// ------ K2: 1x1 in_proj, 32x32x16 MFMA, even/odd interleaved voxel tiles ------
__global__ __launch_bounds__(256) void k2_mfma(const u16* __restrict__ xb,
    const u16* __restrict__ Wp, const float* __restrict__ biasp,
    u16* __restrict__ xp) {
  const int lane = threadIdx.x & 63, wid = threadIdx.x >> 6;
  const int n = lane & 31, hf = lane >> 5;
  const int v0 = blockIdx.x * 256 + wid * 64;      // 64 voxels per wave
  bf16x8 A[2][4];                                  // [o-tile][k-slice]
  #pragma unroll
  for (int t = 0; t < 2; ++t)
    #pragma unroll
    for (int s = 0; s < 4; ++s)
      A[t][s] = *(const bf16x8*)(Wp + (t * 32 + n) * C + s * 16 + hf * 8);

  f32x16 accE[2], accO[2];
  #pragma unroll
  for (int t = 0; t < 2; ++t)
    #pragma unroll
    for (int r = 0; r < 16; ++r) {
      const float b = biasp[t * 32 + (r & 3) + 8 * (r >> 2) + 4 * hf];
      accE[t][r] = b; accO[t][r] = b;
    }

  #pragma unroll
  for (int s = 0; s < 4; ++s) {
    union { u16 u[8]; bf16x8 v; } BE, BO;
    #pragma unroll
    for (int j = 0; j < 8; ++j) {
      const u32 xv = *(const u32*)(xb + (size_t)(s * 16 + hf * 8 + j) * S + v0 + 2 * n);
      BE.u[j] = (u16)(xv & 0xFFFFu); BO.u[j] = (u16)(xv >> 16);
    }
    #pragma unroll
    for (int t = 0; t < 2; ++t) {
      accE[t] = MFMA32(A[t][s], BE.v, accE[t]);
      accO[t] = MFMA32(A[t][s], BO.v, accO[t]);
    }
  }
  #pragma unroll
  for (int t = 0; t < 2; ++t)
    #pragma unroll
    for (int r = 0; r < 16; ++r) {
      const int o = t * 32 + (r & 3) + 8 * (r >> 2) + 4 * hf;
      *(u32*)(xp + (size_t)o * S + v0 + 2 * n) = cvt_pk_bf16(accE[t][r], accO[t][r]);
    }
}

// ---- depthwise 3x3x3: LDS-staged planes, A/B tap-carry, dbuf, 1 barrier/step -
__device__ __forceinline__ void fma3(float* __restrict__ a,
    const float* __restrict__ r, float t0, float t1, float t2) {
  #pragma unroll
  for (int i = 0; i < 8; ++i) a[i] = fmaf(t0, r[i], a[i]);
  #pragma unroll
  for (int i = 0; i < 8; ++i) a[i] = fmaf(t1, r[i + 1], a[i]);
  #pragma unroll
  for (int i = 0; i < 8; ++i) a[i] = fmaf(t2, r[i + 2], a[i]);
}

// convA: c<32: t1[c] = SiLU(conv_ssm(xp[c])); c>=32: z_hi[c-32] = SiLU(conv_sym(xp[c]))
// convB: z_lo[c] = conv_mamba(t1[c])
// DCHUNKT must be even (2-round unroll keeps LDS buf ids static).
template<bool SILU, int DCHUNKT>
__global__ __launch_bounds__(192) void dwconv(const u16* __restrict__ srcA,
    const float* __restrict__ kwA, const float* __restrict__ bA,
    u16* __restrict__ dstA,
    const float* __restrict__ kwB, const float* __restrict__ bB,
    u16* __restrict__ dstB) {
  __shared__ u16 lds[2][LBUF];
  const int c = blockIdx.z;
  const u16* src = srcA + (size_t)c * S;
  u16* dst; const float* kwp; float bias;
  if (c < HALF) { dst = dstA + (size_t)c * S;          kwp = kwA + c * 27;          bias = bA[c]; }
  else          { dst = dstB + (size_t)(c - HALF) * S; kwp = kwB + (c - HALF) * 27; bias = bB[c - HALF]; }
  float kw[27];                            // wave-uniform
  #pragma unroll
  for (int i = 0; i < 27; ++i) kw[i] = kwp[i];

  const int tx = threadIdx.x, ty = threadIdx.y;    // 12 x 16
  const int tid = ty * 12 + tx;
  const int w8 = tx * 8;
  const int h0 = blockIdx.x * 16;
  const int d0 = blockIdx.y * DCHUNKT;

  // zero the pad chunks once (offsets 104*k, k=0..18, both buffers); never rewritten
  if (tid < 38) {
    const int b = tid / 19, k = tid % 19;
    *(u16x8*)&lds[b][RPAD * k] = zero8();
  }

  // staging assignment: chunk c0 = tid, chunk c1 = 192+tid (tid<24). 216 = 18x12.
  const int s_row0 = tid / 12, s_cc0 = tid % 12;
  const int s_row1 = (192 + tid) / 12, s_cc1 = (192 + tid) % 12;
  const bool has2 = tid < 24;
  const int s_h0 = h0 - 1 + s_row0;
  const int s_h1 = h0 - 1 + s_row1;
  const bool h0ok = (unsigned)s_h0 < DIM;
  const bool h1ok = has2 && ((unsigned)s_h1 < DIM);
  u16x8 vs0, vs1;

  #define STAGE_LOAD(DD) { \
    vs0 = zero8(); vs1 = zero8(); \
    if (((unsigned)(DD) < DIM) && h0ok) \
      vs0 = *(const u16x8*)(src + (size_t)(DD) * PLANE + s_h0 * DIM + s_cc0 * 8); \
    if (((unsigned)(DD) < DIM) && h1ok) \
      vs1 = *(const u16x8*)(src + (size_t)(DD) * PLANE + s_h1 * DIM + s_cc1 * 8); }

  #define STAGE_WRITE(WB) { \
    *(u16x8*)&lds[WB][8 + s_row0 * RPAD + s_cc0 * 8] = vs0; \
    if (has2) *(u16x8*)&lds[WB][8 + s_row1 * RPAD + s_cc1 * 8] = vs1; }

  float r0[10], r1[10], r2[10];
  float A[8], B[8], o8[8];

  // LDS window read: pads make w=-1 / w=96 / row-head all hit zero chunks.
  #define LOADROW(R, ROWI, RB) { \
    const u16* _lb = &lds[RB][8 + (ROWI) * RPAD + w8]; \
    const u16x8 _m = *(const u16x8*)_lb; \
    const u16 _lo = _lb[-1], _hi = _lb[8]; \
    R[0] = bf2f(_lo); \
    _Pragma("unroll") \
    for (int i = 0; i < 8; ++i) R[1 + i] = bf2f(_m[i]); \
    R[9] = bf2f(_hi); }

  #define LOADROWS(RB) { LOADROW(r0, ty, RB); LOADROW(r1, ty + 1, RB); LOADROW(r2, ty + 2, RB); }

  #define CBLK(ACC, K0) { \
    fma3(ACC, r0, kw[(K0) + 0], kw[(K0) + 1], kw[(K0) + 2]); \
    fma3(ACC, r1, kw[(K0) + 3], kw[(K0) + 4], kw[(K0) + 5]); \
    fma3(ACC, r2, kw[(K0) + 6], kw[(K0) + 7], kw[(K0) + 8]); }

  // ---- prologue ----
  STAGE_LOAD(d0 - 1);            // d0==0 -> zeros (bounds check)
  STAGE_WRITE(0);
  __syncthreads();

  LOADROWS(0);                   // plane d0-1
  STAGE_LOAD(d0);
  #pragma unroll
  for (int i = 0; i < 8; ++i) B[i] = bias;
  CBLK(B, 0);
  STAGE_WRITE(1);
  __syncthreads();

  LOADROWS(1);                   // plane d0
  STAGE_LOAD(d0 + 1);
  #pragma unroll
  for (int i = 0; i < 8; ++i) { A[i] = B[i]; B[i] = bias; }
  CBLK(A, 9);
  CBLK(B, 0);
  STAGE_WRITE(0);
  __syncthreads();

  // ---- main: round(d): read buf[(d-d0)&1], output d, stage plane d+2 ----
  u16* db = dst + (size_t)d0 * PLANE + (size_t)(h0 + ty) * DIM + w8;

  #define ROUND_BODY(D, RB, WB, DO_STG) { \
    LOADROWS(RB); \
    if (DO_STG) STAGE_LOAD((D) + 2); \
    _Pragma("unroll") \
    for (int i = 0; i < 8; ++i) o8[i] = A[i]; \
    CBLK(o8, 18); \
    _Pragma("unroll") \
    for (int i = 0; i < 8; ++i) A[i] = B[i]; \
    CBLK(A, 9); \
    _Pragma("unroll") \
    for (int i = 0; i < 8; ++i) B[i] = bias; \
    CBLK(B, 0); \
    if (SILU) { \
      _Pragma("unroll") \
      for (int i = 0; i < 8; ++i) o8[i] = silu(o8[i]); \
    } \
    union { u32 u[4]; u16x8 v; } _o; \
    _Pragma("unroll") \
    for (int i = 0; i < 4; ++i) _o.u[i] = cvt_pk_bf16(o8[2 * i], o8[2 * i + 1]); \
    *(u16x8*)db = _o.v; \
    db += PLANE; \
    if (DO_STG) STAGE_WRITE(WB); \
    __syncthreads(); }

  #pragma unroll 1
  for (int d = d0; d < d0 + DCHUNKT; d += 2) {
    ROUND_BODY(d, 0, 1, true);                                   // output d
    ROUND_BODY(d + 1, 1, 0, (d + 2) < d0 + DCHUNKT);             // output d+1
  }
  #undef ROUND_BODY
  #undef CBLK
  #undef LOADROWS
  #undef LOADROW
  #undef STAGE_WRITE
  #undef STAGE_LOAD
}

// --- K4b: 1x1 out_proj (32x32x16 MFMA) + bias + bf16 residual -> fp32 out -----
__global__ __launch_bounds__(256) void k4b_mfma(const u16* __restrict__ z_lo,
    const u16* __restrict__ z_hi, const u16* __restrict__ xb,
    const u16* __restrict__ Wo, const float* __restrict__ ob,
    float* __restrict__ out) {
  const int lane = threadIdx.x & 63, wid = threadIdx.x >> 6;
  const int n = lane & 31, hf = lane >> 5;
  const int v0 = blockIdx.x * 256 + wid * 64;
  bf16x8 A[2][4];
  #pragma unroll
  for (int t = 0; t < 2; ++t)
    #pragma unroll
    for (int s = 0; s < 4; ++s)
      A[t][s] = *(const bf16x8*)(Wo + (t * 32 + n) * C + s * 16 + hf * 8);

  f32x16 accE[2], accO[2];
  #pragma unroll
  for (int t = 0; t < 2; ++t)
    #pragma unroll
    for (int r = 0; r < 16; ++r) {
      const float b = ob[t * 32 + (r & 3) + 8 * (r >> 2) + 4 * hf];
      accE[t][r] = b; accO[t][r] = b;
    }

  #pragma unroll
  for (int s = 0; s < 4; ++s) {
    const u16* zbase = (s < 2) ? z_lo + (size_t)(s * 16) * S
                               : z_hi + (size_t)((s - 2) * 16) * S;
    union { u16 u[8]; bf16x8 v; } BE, BO;
    #pragma unroll
    for (int j = 0; j < 8; ++j) {
      const u32 zv = *(const u32*)(zbase + (size_t)(hf * 8 + j) * S + v0 + 2 * n);
      BE.u[j] = (u16)(zv & 0xFFFFu); BO.u[j] = (u16)(zv >> 16);
    }
    #pragma unroll
    for (int t = 0; t < 2; ++t) {
      accE[t] = MFMA32(A[t][s], BE.v, accE[t]);
      accO[t] = MFMA32(A[t][s], BO.v, accO[t]);
    }
  }
  #pragma unroll
  for (int t = 0; t < 2; ++t)
    #pragma unroll
    for (int r = 0; r < 16; ++r) {
      const int o = t * 32 + (r & 3) + 8 * (r >> 2) + 4 * hf;
      const u32 xr = *(const u32*)(xb + (size_t)o * S + v0 + 2 * n);
      float2 ov;
      ov.x = accE[t][r] + bf2f((u16)(xr & 0xFFFFu));
      ov.y = accO[t][r] + bf2f((u16)(xr >> 16));
      *(float2*)(out + (size_t)o * S + v0 + 2 * n) = ov;
    }
}

extern "C" void kernel_launch(void* const* d_in, const int* in_sizes, int n_in,
                              void* d_out, int out_size, void* d_ws, size_t ws_size,
                              hipStream_t stream) {
  const float* x      = (const float*)d_in[0];
  const float* norm_w = (const float*)d_in[1];
  const float* norm_b = (const float*)d_in[2];
  const float* in_w   = (const float*)d_in[3];
  const float* in_b   = (const float*)d_in[4];
  const float* ssm_w  = (const float*)d_in[5];
  const float* ssm_b  = (const float*)d_in[6];
  const float* mam_w  = (const float*)d_in[7];
  const float* mam_b  = (const float*)d_in[8];
  const float* sym_w  = (const float*)d_in[9];
  const float* sym_b  = (const float*)d_in[10];
  const float* out_w  = (const float*)d_in[11];
  const float* out_b  = (const float*)d_in[12];
  float* out = (float*)d_out;

  // Workspace (u16 units). z_lo ALIASES xp[0:32] (dead after convA; convB is
  // launched after convA completes, stream-ordered). Total ~340 MB.
  u16* xb   = (u16*)d_ws;                      // C*S bf16 copy of x (113.2 MB)
  u16* xp   = xb + (size_t)C * S;              // C*S bf16 (113.2 MB)
  u16* t1   = xp + (size_t)C * S;              // HALF*S bf16 (56.6 MB)
  u16* z_hi = t1 + (size_t)HALF * S;           // HALF*S bf16 (56.6 MB)
  u16* z_lo = xp;                              // alias, HALF*S
  float* psum  = (float*)(z_hi + (size_t)HALF * S);  // C*PARTS
  float* psq   = psum + C * PARTS;             // C*PARTS
  u16* Wp      = (u16*)(psq + C * PARTS);      // C*C bf16
  u16* Wo      = Wp + C * C;                   // C*C bf16
  float* biasp = (float*)(Wo + C * C);         // C fp32

  k1_stats<<<C * PARTS, 256, 0, stream>>>(x, xb, psum, psq);
  k1b_prep<<<1, 64, 0, stream>>>(psum, psq, norm_w, norm_b, in_w, in_b, out_w,
                                 Wp, biasp, Wo);
  k2_mfma<<<S / 256, 256, 0, stream>>>(xb, Wp, biasp, xp);
  // convA: ssm on xp[0:32] -> t1 ; sym on xp[32:64] -> z_hi (both SiLU); 24-chunks
  dwconv<true, 24><<<dim3(DIM / 16, 4, C), dim3(12, 16, 1), 0, stream>>>(
      xp, ssm_w, ssm_b, t1, sym_w, sym_b, z_hi);
  // convB: mamba on t1 -> z_lo (no activation); 12-chunks -> 2x blocks for TLP
  dwconv<false, 12><<<dim3(DIM / 16, 8, HALF), dim3(12, 16, 1), 0, stream>>>(
      t1, mam_w, mam_b, z_lo, mam_w, mam_b, z_lo);
  k4b_mfma<<<S / 256, 256, 0, stream>>>(z_lo, z_hi, xb, Wo, out_b, out);
}